// Round 4
// baseline (916.808 us; speedup 1.0000x reference)
//
#include <hip/hip_runtime.h>
#include <hip/hip_bf16.h>

#define BB 2
#define NN 4096
#define CH 64
#define KW 8            // waves (slices) per KNN block
#define KSL (NN / KW)   // 512 points per slice

typedef __bf16 bf16x8 __attribute__((ext_vector_type(8)));
typedef float f32x4 __attribute__((ext_vector_type(4)));

__device__ __forceinline__ float lrelu(float v) { return fmaxf(v, 0.1f * v); }
__device__ __forceinline__ float tobf(const __hip_bfloat16& h) { return __bfloat162float(h); }

// canonical f32 input region offsets (element offsets within cn)
#define PC1_C 0
#define PC2_C 24576
#define F1_C 49152
#define F2_C 573440
#define K1_C 1097728
#define K2_C 1622016
#define WT11_C 2146304
#define BT11_C 2150400
#define WT22_C 2150464
#define BT22_C 2154560
#define WPOS_C 2154624
#define BPOS_C 2154816
#define WM1_C 2154880
#define BM1_C 2158976
#define WM2_C 2159040
#define BM2_C 2163136
#define CN_TOTAL 2163200

// bubble-insert into sorted ascending top-8; compile-time indices (stays in regs)
__device__ __forceinline__ void insert8(float bd[8], int bi[8], float nd, int ni) {
#pragma unroll
  for (int p = 0; p < 8; ++p) {
    bool c = nd < bd[p];
    float td = c ? nd : bd[p];
    int ti = c ? ni : bi[p];
    nd = c ? bd[p] : nd;
    ni = c ? bi[p] : ni;
    bd[p] = td;
    bi[p] = ti;
  }
}

// ---- dtype detector: interpret pc1's first 4096 u16 words as bf16; f32 data's
// low mantissa halves produce ~45% exponents >= 140; true bf16 N(0,1) gives ~0.
__global__ void k_detect(const unsigned short* __restrict__ pc1raw, int* __restrict__ flag) {
  int lane = threadIdx.x;  // 64
  int bad = 0;
#pragma unroll
  for (int i = 0; i < 64; ++i) {
    unsigned short u = pc1raw[lane * 64 + i];
    int e = (u >> 7) & 0xFF;
    bad += (e >= 140) ? 1 : 0;  // |v| >= 2^13 or Inf/NaN
  }
#pragma unroll
  for (int s = 32; s; s >>= 1) bad += __shfl_xor(bad, s, 64);
  if (lane == 0) *flag = (bad > 16) ? 1 : 0;  // 1 = inputs are float32
}

// ---- ingest: convert all 16 inputs to canonical f32 (exact either way) + sanitize
__global__ __launch_bounds__(256) void k_ingest(
    const void* p0, const void* p1, const void* p2, const void* p3,
    const void* p4, const void* p5, const void* p6, const void* p7,
    const void* p8, const void* p9, const void* p10, const void* p11,
    const void* p12, const void* p13, const void* p14, const void* p15,
    const int* __restrict__ flag, float* __restrict__ dst) {
  const int cum[17] = {0, 24576, 49152, 573440, 1097728, 1622016, 2146304, 2150400,
                       2150464, 2154560, 2154624, 2154816, 2154880, 2158976, 2159040,
                       2163136, 2163200};
  size_t t = (size_t)blockIdx.x * 256 + threadIdx.x;
  if (t >= (size_t)CN_TOTAL) return;
  int seg = 0;
#pragma unroll
  for (int i = 1; i < 16; ++i) seg += (t >= (size_t)cum[i]) ? 1 : 0;
  size_t local = t - (size_t)cum[seg];
  const void* ptrs[16] = {p0, p1, p2, p3, p4, p5, p6, p7, p8, p9, p10, p11, p12, p13, p14, p15};
  const void* p = ptrs[seg];
  float v;
  if (*flag) v = ((const float*)p)[local];
  else       v = tobf(((const __hip_bfloat16*)p)[local]);
  if (!(v == v) || fabsf(v) > 1e30f) v = 0.f;  // sanitize (no-op on clean data)
  dst[t] = v;
}

// ---- Wm1/Wm2 -> bf16 canonical (row-major, Wm1 at [0,4096), Wm2 at [4096,8192))
__global__ void k_prep_wm(const float* __restrict__ cn, __hip_bfloat16* __restrict__ wmb) {
  int t = blockIdx.x * 256 + threadIdx.x;  // 8192
  float v = (t < 4096) ? cn[WM1_C + t] : cn[WM2_C + (t - 4096)];
  wmb[t] = __float2bfloat16(v);
}

// ---- prep: pc [B,3,N] f32 -> float4(x,y,z,|p|^2) [2][B][N]
__global__ __launch_bounds__(256) void k_prep_xyz(const float* __restrict__ cn,
                                                  float4* __restrict__ xyzt) {
  int t = blockIdx.x * 256 + threadIdx.x;  // 2*BB*NN threads
  int n = t & (NN - 1);
  int b = (t >> 12) & 1;
  int a = t >> 13;
  const float* p = cn + (a ? PC2_C : PC1_C) + (size_t)b * 3 * NN + n;
  float x = p[0], y = p[NN], z = p[2 * NN];
  xyzt[(size_t)(a * BB + b) * NN + n] = make_float4(x, y, z, x * x + y * y + z * z);
}

// ---- prep: W_pos [64,3] + b_pos [64] -> float4 per channel
__global__ void k_prep_wpos(const float* __restrict__ cn, float4* __restrict__ wp4) {
  int c = threadIdx.x;  // 64
  wp4[c] = make_float4(cn[WPOS_C + 3 * c], cn[WPOS_C + 3 * c + 1], cn[WPOS_C + 3 * c + 2],
                       cn[BPOS_C + c]);
}

// ---- prep: knn [B,64,N] f32 -> row-normalized f32 [2][B][N][64]  (ref: x/sqrt(sum+1e-8))
__global__ __launch_bounds__(256) void k_prep_knn(const float* __restrict__ cn,
                                                  float* __restrict__ knnt) {
  int t = blockIdx.x * 256 + threadIdx.x;  // 2*BB*NN
  int n = t & (NN - 1);
  int b = (t >> 12) & 1;
  int a = t >> 13;
  const float* col = cn + (a ? K2_C : K1_C) + (size_t)b * CH * NN + n;
  float s = 0.f;
#pragma unroll
  for (int c = 0; c < CH; ++c) { float v = col[(size_t)c * NN]; s += v * v; }
  float inv = 1.0f / sqrtf(s + 1e-8f);
  float* o = knnt + ((size_t)(a * BB + b) * NN + n) * CH;
#pragma unroll
  for (int c = 0; c < CH; ++c) o[c] = col[(size_t)c * NN] * inv;
}

// ---- 1x1 convs: fbuf[sel][b][n][64], sel: 0=f1a(W11,f1) 1=f2a(W22,f2) 2=f2b(W11,f2) 3=f1b(W22,f1)
__global__ __launch_bounds__(256) void k_conv(const float* __restrict__ cn,
                                              float* __restrict__ fbuf) {
  __shared__ float wl[CH * CH];  // [c][d]
  int bid = blockIdx.x;          // 4*BB*(NN/4)
  int tile = bid & (NN / 4 - 1);
  int b = (bid >> 10) & 1;
  int sel = bid >> 11;
  const float* W = cn + ((sel == 0 || sel == 2) ? WT11_C : WT22_C);
  const float* bias = cn + ((sel == 0 || sel == 2) ? BT11_C : BT22_C);
  const float* feat = cn + ((sel == 0 || sel == 3) ? F1_C : F2_C);
  int t = threadIdx.x;
#pragma unroll
  for (int i = 0; i < 16; ++i) {
    int e = t * 16 + i;  // W[d][c] row-major -> wl[c][d]
    wl[(e & 63) * 64 + (e >> 6)] = W[e];
  }
  __syncthreads();
  int p = t >> 6, d = t & 63;
  int n = tile * 4 + p;
  const float* fc = feat + (size_t)b * CH * NN + n;
  float acc = bias[d];
#pragma unroll
  for (int c = 0; c < CH; ++c) acc += wl[c * 64 + d] * fc[(size_t)c * NN];
  fbuf[((size_t)(sel * BB + b) * NN + n) * CH + d] = acc;
}

// ---- fused KNN (cos + euclid), in-block slice merge, no global candidate buffers.
// Block = 8 waves x 64 lanes. Lane = query (64 queries/block), wave = DB slice of 512.
__global__ __launch_bounds__(512) void k_knn(const float* __restrict__ knnt,
                                             const float4* __restrict__ xyzt,
                                             int* __restrict__ idxf) {
  __shared__ float cds[KW * 64 * 8];  // 16 KB
  __shared__ int   cis[KW * 64 * 8];  // 16 KB
  int bid = blockIdx.x;  // 2*BB*(NN/64) = 256
  int qt = bid & 63;
  int b = (bid >> 6) & 1;
  int x = bid >> 7;
  int w = threadIdx.x >> 6;
  int lane = threadIdx.x & 63;
  int q = qt * 64 + lane;
  int j0 = w * KSL;

  float bd[8]; int bi[8];

  // ---- phase 1: cosine scan over this wave's slice
  {
    const float4* qp = reinterpret_cast<const float4*>(knnt + ((size_t)(x * BB + b) * NN + q) * CH);
    float4 qv[16];
#pragma unroll
    for (int i = 0; i < 16; ++i) qv[i] = qp[i];
    const float* db = knnt + (size_t)((1 - x) * BB + b) * NN * CH;
#pragma unroll
    for (int k = 0; k < 8; ++k) { bd[k] = 1e30f; bi[k] = 0; }
    for (int j = j0; j < j0 + KSL; ++j) {
      const float4* dp = reinterpret_cast<const float4*>(db + (size_t)j * CH);
      float ax = 0.f, ay = 0.f, az = 0.f, aw = 0.f;
#pragma unroll
      for (int i = 0; i < 16; ++i) {
        float4 dv = dp[i];  // wave-uniform address
        ax += dv.x * qv[i].x; ay += dv.y * qv[i].y;
        az += dv.z * qv[i].z; aw += dv.w * qv[i].w;
      }
      float dist = 1.0f - ((ax + ay) + (az + aw));
      if (dist < bd[7]) insert8(bd, bi, dist, j);
    }
#pragma unroll
    for (int k = 0; k < 8; ++k) { cds[(w * 64 + lane) * 8 + k] = bd[k]; cis[(w * 64 + lane) * 8 + k] = bi[k]; }
  }
  __syncthreads();
  if (w == 0) {  // merge cosine candidates for this lane's query
#pragma unroll
    for (int k = 0; k < 8; ++k) { bd[k] = 1e30f; bi[k] = 0; }
    for (int c = 0; c < KW * 8; ++c) {
      int ww = c >> 3, k = c & 7;
      float d = cds[(ww * 64 + lane) * 8 + k];
      if (d < bd[7]) insert8(bd, bi, d, cis[(ww * 64 + lane) * 8 + k]);
    }
    int* o = idxf + (((size_t)x * BB + b) * NN + q) * 16;
#pragma unroll
    for (int k = 0; k < 8; ++k) o[k] = bi[k];
  }
  __syncthreads();

  // ---- phase 2: euclid scan (reuse LDS)
  {
    float4 q4 = xyzt[(size_t)(x * BB + b) * NN + q];
    const float4* dbx = xyzt + (size_t)((1 - x) * BB + b) * NN;
#pragma unroll
    for (int k = 0; k < 8; ++k) { bd[k] = 1e30f; bi[k] = 0; }
    for (int j = j0; j < j0 + KSL; ++j) {
      float4 p = dbx[j];  // wave-uniform
      float dist = q4.w + p.w - 2.f * (q4.x * p.x + q4.y * p.y + q4.z * p.z);
      if (dist < bd[7]) insert8(bd, bi, dist, j);
    }
#pragma unroll
    for (int k = 0; k < 8; ++k) { cds[(w * 64 + lane) * 8 + k] = bd[k]; cis[(w * 64 + lane) * 8 + k] = bi[k]; }
  }
  __syncthreads();
  if (w == 0) {
#pragma unroll
    for (int k = 0; k < 8; ++k) { bd[k] = 1e30f; bi[k] = 0; }
    for (int c = 0; c < KW * 8; ++c) {
      int ww = c >> 3, k = c & 7;
      float d = cds[(ww * 64 + lane) * 8 + k];
      if (d < bd[7]) insert8(bd, bi, d, cis[(ww * 64 + lane) * 8 + k]);
    }
    int* o = idxf + (((size_t)x * BB + b) * NN + q) * 16 + 8;
#pragma unroll
    for (int k = 0; k < 8; ++k) o[k] = bi[k];
  }
}

// ---- fused gather + pos-conv + 2x MFMA MLP + neighbor max. One wave per query.
// M=16 neighbors, N=16-ch chunks (x4), K=32 (x2). A-frag: m=lane&15, k=(lane>>4)*8+j.
// B-frag: n=lane&15, k=(lane>>4)*8+j. D: col=lane&15, row=(lane>>4)*4+reg (m89/m120).
// Output: FLOAT32 (reference returns jnp.float32).
__global__ __launch_bounds__(256) void k_mlp(const float* __restrict__ fbuf,
                                             const float4* __restrict__ xyzt,
                                             const int* __restrict__ idxf,
                                             const float4* __restrict__ wp4,
                                             const __hip_bfloat16* __restrict__ wmb,
                                             const float* __restrict__ cn,
                                             float* __restrict__ out) {
  __shared__ __bf16 h1s[4 * 16 * 72];  // per-wave 16 rows x stride 72 (16B-aligned rows)
  const int t = threadIdx.x;
  const int wv = t >> 6, L = t & 63;
  const int lo = L & 15, g = L >> 4;
  int bid = blockIdx.x;  // 2*BB*(NN/4) = 4096
  const int qt = bid & (NN / 4 - 1);
  const int b = (bid >> 10) & 1;
  const int x = bid >> 11;
  const int q = qt * 4 + wv;

  // weight B-fragments resident in VGPRs: frag[tt][kc][j] = W[tt*16+lo][kc*32+g*8+j]
  bf16x8 w1f[4][2], w2f[4][2];
#pragma unroll
  for (int tt = 0; tt < 4; ++tt)
#pragma unroll
    for (int kc = 0; kc < 2; ++kc) {
      int e = tt * 16 + lo, c0 = kc * 32 + g * 8;
      w1f[tt][kc] = *reinterpret_cast<const bf16x8*>(wmb + e * 64 + c0);
      w2f[tt][kc] = *reinterpret_cast<const bf16x8*>(wmb + 4096 + e * 64 + c0);
    }

  const float* pq  = fbuf + ((size_t)((x ? 2 : 0) * BB + b)) * NN * CH;
  const float* pdb = fbuf + ((size_t)((x ? 3 : 1) * BB + b)) * NN * CH;
  const float4* qx  = xyzt + (size_t)(x * BB + b) * NN;
  const float4* dbx = xyzt + (size_t)((1 - x) * BB + b) * NN;

  const int m = lo;  // this lane's neighbor slot
  int jm = idxf[(((size_t)x * BB + b) * NN + q) * 16 + m];
  jm &= (NN - 1);  // defensive clamp: garbage idx -> finite-wrong, never OOB
  const float4 q4 = qx[q];
  const float4 p4 = dbx[jm];
  const float dx = p4.x - q4.x, dy = p4.y - q4.y, dz = p4.z - q4.z;
  const float* g2p = pdb + (size_t)jm * CH;
  const float* pqp = pq + (size_t)q * CH;

  // H0 built directly in A-fragment layout
  bf16x8 a0, a1;
#pragma unroll
  for (int kc = 0; kc < 2; ++kc) {
#pragma unroll
    for (int j = 0; j < 8; ++j) {
      int c = kc * 32 + g * 8 + j;
      float4 wp = wp4[c];
      float v = g2p[c] + pqp[c] + wp.x * dx + wp.y * dy + wp.z * dz + wp.w;
      v = lrelu(v);
      if (kc == 0) a0[j] = (__bf16)v; else a1[j] = (__bf16)v;
    }
  }

  // layer 1 -> LDS (D-layout write, A-layout read)
  __bf16* hrow = h1s + wv * 16 * 72;
#pragma unroll
  for (int tt = 0; tt < 4; ++tt) {
    float bv = cn[BM1_C + tt * 16 + lo];
    f32x4 acc = {bv, bv, bv, bv};
    acc = __builtin_amdgcn_mfma_f32_16x16x32_bf16(a0, w1f[tt][0], acc, 0, 0, 0);
    acc = __builtin_amdgcn_mfma_f32_16x16x32_bf16(a1, w1f[tt][1], acc, 0, 0, 0);
#pragma unroll
    for (int r = 0; r < 4; ++r) {
      float v = lrelu(acc[r]);
      hrow[(g * 4 + r) * 72 + tt * 16 + lo] = (__bf16)v;
    }
  }
  __syncthreads();
  bf16x8 h1a = *reinterpret_cast<const bf16x8*>(hrow + m * 72 + g * 8);
  bf16x8 h1b = *reinterpret_cast<const bf16x8*>(hrow + m * 72 + 32 + g * 8);

  // layer 2 + max over neighbors + store (f32)
  size_t obase = ((size_t)(x * BB + b) * CH) * NN;
#pragma unroll
  for (int tt = 0; tt < 4; ++tt) {
    float bv = cn[BM2_C + tt * 16 + lo];
    f32x4 acc = {bv, bv, bv, bv};
    acc = __builtin_amdgcn_mfma_f32_16x16x32_bf16(h1a, w2f[tt][0], acc, 0, 0, 0);
    acc = __builtin_amdgcn_mfma_f32_16x16x32_bf16(h1b, w2f[tt][1], acc, 0, 0, 0);
    float v = fmaxf(fmaxf(lrelu(acc[0]), lrelu(acc[1])), fmaxf(lrelu(acc[2]), lrelu(acc[3])));
    v = fmaxf(v, __shfl_xor(v, 16, 64));
    v = fmaxf(v, __shfl_xor(v, 32, 64));
    if (g == 0) out[obase + (size_t)(tt * 16 + lo) * NN + q] = v;
  }
}

// workspace layout (float units) — total ~5.64M floats = 22.6 MB
#define CN_OFF 0
#define FB_OFF ((size_t)CN_TOTAL)                      // 2,163,200
#define KT_OFF (FB_OFF + (size_t)4 * BB * NN * CH)     // +2,097,152
#define XZ_OFF (KT_OFF + (size_t)2 * BB * NN * CH)     // +1,048,576
#define WP4_OFF (XZ_OFF + (size_t)2 * BB * NN * 4)     // +65,536
#define WMB_OFF (WP4_OFF + 256)                        // 8192 bf16 = 4096 floats
#define IDX_OFF (WMB_OFF + 4096)                       // 262,144 ints
#define FLAG_OFF (IDX_OFF + 262144)                    // 1 int

extern "C" void kernel_launch(void* const* d_in, const int* in_sizes, int n_in,
                              void* d_out, int out_size, void* d_ws, size_t ws_size,
                              hipStream_t stream) {
  float* ws = (float*)d_ws;
  float* cn = ws + CN_OFF;
  int* flag = (int*)(ws + FLAG_OFF);

  k_detect<<<1, 64, 0, stream>>>((const unsigned short*)d_in[0], flag);
  k_ingest<<<(CN_TOTAL + 255) / 256, 256, 0, stream>>>(
      d_in[0], d_in[1], d_in[2], d_in[3], d_in[4], d_in[5], d_in[6], d_in[7],
      d_in[8], d_in[9], d_in[10], d_in[11], d_in[12], d_in[13], d_in[14], d_in[15],
      flag, cn);
  k_prep_wm<<<32, 256, 0, stream>>>(cn, (__hip_bfloat16*)(ws + WMB_OFF));
  k_prep_xyz<<<(2 * BB * NN) / 256, 256, 0, stream>>>(cn, (float4*)(ws + XZ_OFF));
  k_prep_wpos<<<1, 64, 0, stream>>>(cn, (float4*)(ws + WP4_OFF));
  k_prep_knn<<<(2 * BB * NN) / 256, 256, 0, stream>>>(cn, ws + KT_OFF);
  k_conv<<<4 * BB * (NN / 4), 256, 0, stream>>>(cn, ws + FB_OFF);
  k_knn<<<2 * BB * (NN / 64), 512, 0, stream>>>(ws + KT_OFF, (const float4*)(ws + XZ_OFF),
                                                (int*)(ws + IDX_OFF));
  k_mlp<<<2 * BB * (NN / 4), 256, 0, stream>>>(ws + FB_OFF, (const float4*)(ws + XZ_OFF),
                                               (const int*)(ws + IDX_OFF), (const float4*)(ws + WP4_OFF),
                                               (const __hip_bfloat16*)(ws + WMB_OFF), cn,
                                               (float*)d_out);
}

// Round 5
// 888.337 us; speedup vs baseline: 1.0321x; 1.0321x over previous
//
#include <hip/hip_runtime.h>
#include <hip/hip_bf16.h>

#define BB 2
#define NN 4096
#define CH 64
#define KW 8            // waves (slices) per KNN block
#define KSL (NN / KW)   // 512 points per slice

typedef __bf16 bf16x8 __attribute__((ext_vector_type(8)));
typedef float f32x4 __attribute__((ext_vector_type(4)));

__device__ __forceinline__ float lrelu(float v) { return fmaxf(v, 0.1f * v); }
__device__ __forceinline__ float tobf(const __hip_bfloat16& h) { return __bfloat162float(h); }

// canonical f32 input region offsets (element offsets within cn)
#define PC1_C 0
#define PC2_C 24576
#define F1_C 49152
#define F2_C 573440
#define K1_C 1097728
#define K2_C 1622016
#define WT11_C 2146304
#define BT11_C 2150400
#define WT22_C 2150464
#define BT22_C 2154560
#define WPOS_C 2154624
#define BPOS_C 2154816
#define WM1_C 2154880
#define BM1_C 2158976
#define WM2_C 2159040
#define BM2_C 2163136
#define CN_TOTAL 2163200

// bubble-insert into sorted ascending top-8; compile-time indices (stays in regs)
__device__ __forceinline__ void insert8(float bd[8], int bi[8], float nd, int ni) {
#pragma unroll
  for (int p = 0; p < 8; ++p) {
    bool c = nd < bd[p];
    float td = c ? nd : bd[p];
    int ti = c ? ni : bi[p];
    nd = c ? bd[p] : nd;
    ni = c ? bi[p] : ni;
    bd[p] = td;
    bi[p] = ti;
  }
}

// ---- dtype detector: interpret pc1's first 4096 u16 words as bf16; f32 data's
// low mantissa halves produce ~45% exponents >= 140; true bf16 N(0,1) gives ~0.
__global__ void k_detect(const unsigned short* __restrict__ pc1raw, int* __restrict__ flag) {
  int lane = threadIdx.x;  // 64
  int bad = 0;
#pragma unroll
  for (int i = 0; i < 64; ++i) {
    unsigned short u = pc1raw[lane * 64 + i];
    int e = (u >> 7) & 0xFF;
    bad += (e >= 140) ? 1 : 0;  // |v| >= 2^13 or Inf/NaN
  }
#pragma unroll
  for (int s = 32; s; s >>= 1) bad += __shfl_xor(bad, s, 64);
  if (lane == 0) *flag = (bad > 16) ? 1 : 0;  // 1 = inputs are float32
}

// ---- ingest: convert all 16 inputs to canonical f32 (exact either way) + sanitize
__global__ __launch_bounds__(256) void k_ingest(
    const void* p0, const void* p1, const void* p2, const void* p3,
    const void* p4, const void* p5, const void* p6, const void* p7,
    const void* p8, const void* p9, const void* p10, const void* p11,
    const void* p12, const void* p13, const void* p14, const void* p15,
    const int* __restrict__ flag, float* __restrict__ dst) {
  const int cum[17] = {0, 24576, 49152, 573440, 1097728, 1622016, 2146304, 2150400,
                       2150464, 2154560, 2154624, 2154816, 2154880, 2158976, 2159040,
                       2163136, 2163200};
  size_t t = (size_t)blockIdx.x * 256 + threadIdx.x;
  if (t >= (size_t)CN_TOTAL) return;
  int seg = 0;
#pragma unroll
  for (int i = 1; i < 16; ++i) seg += (t >= (size_t)cum[i]) ? 1 : 0;
  size_t local = t - (size_t)cum[seg];
  const void* ptrs[16] = {p0, p1, p2, p3, p4, p5, p6, p7, p8, p9, p10, p11, p12, p13, p14, p15};
  const void* p = ptrs[seg];
  float v;
  if (*flag) v = ((const float*)p)[local];
  else       v = tobf(((const __hip_bfloat16*)p)[local]);
  if (!(v == v) || fabsf(v) > 1e30f) v = 0.f;  // sanitize (no-op on clean data)
  dst[t] = v;
}

// ---- Wm1/Wm2 -> bf16 canonical (row-major, Wm1 at [0,4096), Wm2 at [4096,8192))
__global__ void k_prep_wm(const float* __restrict__ cn, __hip_bfloat16* __restrict__ wmb) {
  int t = blockIdx.x * 256 + threadIdx.x;  // 8192
  float v = (t < 4096) ? cn[WM1_C + t] : cn[WM2_C + (t - 4096)];
  wmb[t] = __float2bfloat16(v);
}

// ---- prep: pc [B,3,N] f32 -> float4(x,y,z,|p|^2) [2][B][N]
__global__ __launch_bounds__(256) void k_prep_xyz(const float* __restrict__ cn,
                                                  float4* __restrict__ xyzt) {
  int t = blockIdx.x * 256 + threadIdx.x;  // 2*BB*NN threads
  int n = t & (NN - 1);
  int b = (t >> 12) & 1;
  int a = t >> 13;
  const float* p = cn + (a ? PC2_C : PC1_C) + (size_t)b * 3 * NN + n;
  float x = p[0], y = p[NN], z = p[2 * NN];
  xyzt[(size_t)(a * BB + b) * NN + n] = make_float4(x, y, z, x * x + y * y + z * z);
}

// ---- prep: W_pos [64,3] + b_pos [64] -> float4 per channel
__global__ void k_prep_wpos(const float* __restrict__ cn, float4* __restrict__ wp4) {
  int c = threadIdx.x;  // 64
  wp4[c] = make_float4(cn[WPOS_C + 3 * c], cn[WPOS_C + 3 * c + 1], cn[WPOS_C + 3 * c + 2],
                       cn[BPOS_C + c]);
}

// ---- prep: knn [B,64,N] f32 -> row-normalized f32 [2][B][N][64]  (ref: x/sqrt(sum+1e-8))
__global__ __launch_bounds__(256) void k_prep_knn(const float* __restrict__ cn,
                                                  float* __restrict__ knnt) {
  int t = blockIdx.x * 256 + threadIdx.x;  // 2*BB*NN
  int n = t & (NN - 1);
  int b = (t >> 12) & 1;
  int a = t >> 13;
  const float* col = cn + (a ? K2_C : K1_C) + (size_t)b * CH * NN + n;
  float s = 0.f;
#pragma unroll
  for (int c = 0; c < CH; ++c) { float v = col[(size_t)c * NN]; s += v * v; }
  float inv = 1.0f / sqrtf(s + 1e-8f);
  float* o = knnt + ((size_t)(a * BB + b) * NN + n) * CH;
#pragma unroll
  for (int c = 0; c < CH; ++c) o[c] = col[(size_t)c * NN] * inv;
}

// ---- 1x1 convs: fbuf[sel][b][n][64], sel: 0=f1a(W11,f1) 1=f2a(W22,f2) 2=f2b(W11,f2) 3=f1b(W22,f1)
__global__ __launch_bounds__(256) void k_conv(const float* __restrict__ cn,
                                              float* __restrict__ fbuf) {
  __shared__ float wl[CH * CH];  // [c][d]
  int bid = blockIdx.x;          // 4*BB*(NN/4)
  int tile = bid & (NN / 4 - 1);
  int b = (bid >> 10) & 1;
  int sel = bid >> 11;
  const float* W = cn + ((sel == 0 || sel == 2) ? WT11_C : WT22_C);
  const float* bias = cn + ((sel == 0 || sel == 2) ? BT11_C : BT22_C);
  const float* feat = cn + ((sel == 0 || sel == 3) ? F1_C : F2_C);
  int t = threadIdx.x;
#pragma unroll
  for (int i = 0; i < 16; ++i) {
    int e = t * 16 + i;  // W[d][c] row-major -> wl[c][d]
    wl[(e & 63) * 64 + (e >> 6)] = W[e];
  }
  __syncthreads();
  int p = t >> 6, d = t & 63;
  int n = tile * 4 + p;
  const float* fc = feat + (size_t)b * CH * NN + n;
  float acc = bias[d];
#pragma unroll
  for (int c = 0; c < CH; ++c) acc += wl[c * 64 + d] * fc[(size_t)c * NN];
  fbuf[((size_t)(sel * BB + b) * NN + n) * CH + d] = acc;
}

// ---- fused KNN (cos + euclid), in-block slice merge, no global candidate buffers.
// Block = 8 waves x 64 lanes. Lane = query (64 queries/block), wave = DB slice of 512.
// __launch_bounds__(512, 2): geometry gives exactly 2 waves/SIMD (256 blocks = 1/CU),
// so min-waves=2 is free and raises VGPR cap 64->256: qv[16] stays register-resident.
// (R4 evidence: VGPR_Count=68 forced a qv spill; FETCH_SIZE 17.46 GB == predicted
//  spill re-read traffic 17.2 GB. This was the 766 us bottleneck.)
__global__ __launch_bounds__(512, 2) void k_knn(const float* __restrict__ knnt,
                                                const float4* __restrict__ xyzt,
                                                int* __restrict__ idxf) {
  __shared__ float cds[KW * 64 * 8];  // 16 KB
  __shared__ int   cis[KW * 64 * 8];  // 16 KB
  int bid = blockIdx.x;  // 2*BB*(NN/64) = 256
  int qt = bid & 63;
  int b = (bid >> 6) & 1;
  int x = bid >> 7;
  int w = threadIdx.x >> 6;
  int lane = threadIdx.x & 63;
  int q = qt * 64 + lane;
  int j0 = w * KSL;

  float bd[8]; int bi[8];

  // ---- phase 1: cosine scan over this wave's slice
  {
    const float4* qp = reinterpret_cast<const float4*>(knnt + ((size_t)(x * BB + b) * NN + q) * CH);
    float4 qv[16];
#pragma unroll
    for (int i = 0; i < 16; ++i) qv[i] = qp[i];
    const float* db = knnt + (size_t)((1 - x) * BB + b) * NN * CH;
#pragma unroll
    for (int k = 0; k < 8; ++k) { bd[k] = 1e30f; bi[k] = 0; }
#pragma unroll 2
    for (int j = j0; j < j0 + KSL; ++j) {
      const float4* dp = reinterpret_cast<const float4*>(db + (size_t)j * CH);
      float ax = 0.f, ay = 0.f, az = 0.f, aw = 0.f;
#pragma unroll
      for (int i = 0; i < 16; ++i) {
        float4 dv = dp[i];  // wave-uniform address -> scalar-load broadcast
        ax += dv.x * qv[i].x; ay += dv.y * qv[i].y;
        az += dv.z * qv[i].z; aw += dv.w * qv[i].w;
      }
      float dist = 1.0f - ((ax + ay) + (az + aw));
      if (dist < bd[7]) insert8(bd, bi, dist, j);
    }
#pragma unroll
    for (int k = 0; k < 8; ++k) { cds[(w * 64 + lane) * 8 + k] = bd[k]; cis[(w * 64 + lane) * 8 + k] = bi[k]; }
  }
  __syncthreads();
  if (w == 0) {  // merge cosine candidates for this lane's query
#pragma unroll
    for (int k = 0; k < 8; ++k) { bd[k] = 1e30f; bi[k] = 0; }
    for (int c = 0; c < KW * 8; ++c) {
      int ww = c >> 3, k = c & 7;
      float d = cds[(ww * 64 + lane) * 8 + k];
      if (d < bd[7]) insert8(bd, bi, d, cis[(ww * 64 + lane) * 8 + k]);
    }
    int* o = idxf + (((size_t)x * BB + b) * NN + q) * 16;
#pragma unroll
    for (int k = 0; k < 8; ++k) o[k] = bi[k];
  }
  __syncthreads();

  // ---- phase 2: euclid scan (reuse LDS)
  {
    float4 q4 = xyzt[(size_t)(x * BB + b) * NN + q];
    const float4* dbx = xyzt + (size_t)((1 - x) * BB + b) * NN;
#pragma unroll
    for (int k = 0; k < 8; ++k) { bd[k] = 1e30f; bi[k] = 0; }
#pragma unroll 2
    for (int j = j0; j < j0 + KSL; ++j) {
      float4 p = dbx[j];  // wave-uniform
      float dist = q4.w + p.w - 2.f * (q4.x * p.x + q4.y * p.y + q4.z * p.z);
      if (dist < bd[7]) insert8(bd, bi, dist, j);
    }
#pragma unroll
    for (int k = 0; k < 8; ++k) { cds[(w * 64 + lane) * 8 + k] = bd[k]; cis[(w * 64 + lane) * 8 + k] = bi[k]; }
  }
  __syncthreads();
  if (w == 0) {
#pragma unroll
    for (int k = 0; k < 8; ++k) { bd[k] = 1e30f; bi[k] = 0; }
    for (int c = 0; c < KW * 8; ++c) {
      int ww = c >> 3, k = c & 7;
      float d = cds[(ww * 64 + lane) * 8 + k];
      if (d < bd[7]) insert8(bd, bi, d, cis[(ww * 64 + lane) * 8 + k]);
    }
    int* o = idxf + (((size_t)x * BB + b) * NN + q) * 16 + 8;
#pragma unroll
    for (int k = 0; k < 8; ++k) o[k] = bi[k];
  }
}

// ---- fused gather + pos-conv + 2x MFMA MLP + neighbor max. One wave per query.
// M=16 neighbors, N=16-ch chunks (x4), K=32 (x2). A-frag: m=lane&15, k=(lane>>4)*8+j.
// B-frag: n=lane&15, k=(lane>>4)*8+j. D: col=lane&15, row=(lane>>4)*4+reg (m89/m120).
// Output: FLOAT32 (reference returns jnp.float32).
__global__ __launch_bounds__(256) void k_mlp(const float* __restrict__ fbuf,
                                             const float4* __restrict__ xyzt,
                                             const int* __restrict__ idxf,
                                             const float4* __restrict__ wp4,
                                             const __hip_bfloat16* __restrict__ wmb,
                                             const float* __restrict__ cn,
                                             float* __restrict__ out) {
  __shared__ __bf16 h1s[4 * 16 * 72];  // per-wave 16 rows x stride 72 (16B-aligned rows)
  const int t = threadIdx.x;
  const int wv = t >> 6, L = t & 63;
  const int lo = L & 15, g = L >> 4;
  int bid = blockIdx.x;  // 2*BB*(NN/4) = 4096
  const int qt = bid & (NN / 4 - 1);
  const int b = (bid >> 10) & 1;
  const int x = bid >> 11;
  const int q = qt * 4 + wv;

  // weight B-fragments resident in VGPRs: frag[tt][kc][j] = W[tt*16+lo][kc*32+g*8+j]
  bf16x8 w1f[4][2], w2f[4][2];
#pragma unroll
  for (int tt = 0; tt < 4; ++tt)
#pragma unroll
    for (int kc = 0; kc < 2; ++kc) {
      int e = tt * 16 + lo, c0 = kc * 32 + g * 8;
      w1f[tt][kc] = *reinterpret_cast<const bf16x8*>(wmb + e * 64 + c0);
      w2f[tt][kc] = *reinterpret_cast<const bf16x8*>(wmb + 4096 + e * 64 + c0);
    }

  const float* pq  = fbuf + ((size_t)((x ? 2 : 0) * BB + b)) * NN * CH;
  const float* pdb = fbuf + ((size_t)((x ? 3 : 1) * BB + b)) * NN * CH;
  const float4* qx  = xyzt + (size_t)(x * BB + b) * NN;
  const float4* dbx = xyzt + (size_t)((1 - x) * BB + b) * NN;

  const int m = lo;  // this lane's neighbor slot
  int jm = idxf[(((size_t)x * BB + b) * NN + q) * 16 + m];
  jm &= (NN - 1);  // defensive clamp: garbage idx -> finite-wrong, never OOB
  const float4 q4 = qx[q];
  const float4 p4 = dbx[jm];
  const float dx = p4.x - q4.x, dy = p4.y - q4.y, dz = p4.z - q4.z;
  const float* g2p = pdb + (size_t)jm * CH;
  const float* pqp = pq + (size_t)q * CH;

  // H0 built directly in A-fragment layout
  bf16x8 a0, a1;
#pragma unroll
  for (int kc = 0; kc < 2; ++kc) {
#pragma unroll
    for (int j = 0; j < 8; ++j) {
      int c = kc * 32 + g * 8 + j;
      float4 wp = wp4[c];
      float v = g2p[c] + pqp[c] + wp.x * dx + wp.y * dy + wp.z * dz + wp.w;
      v = lrelu(v);
      if (kc == 0) a0[j] = (__bf16)v; else a1[j] = (__bf16)v;
    }
  }

  // layer 1 -> LDS (D-layout write, A-layout read)
  __bf16* hrow = h1s + wv * 16 * 72;
#pragma unroll
  for (int tt = 0; tt < 4; ++tt) {
    float bv = cn[BM1_C + tt * 16 + lo];
    f32x4 acc = {bv, bv, bv, bv};
    acc = __builtin_amdgcn_mfma_f32_16x16x32_bf16(a0, w1f[tt][0], acc, 0, 0, 0);
    acc = __builtin_amdgcn_mfma_f32_16x16x32_bf16(a1, w1f[tt][1], acc, 0, 0, 0);
#pragma unroll
    for (int r = 0; r < 4; ++r) {
      float v = lrelu(acc[r]);
      hrow[(g * 4 + r) * 72 + tt * 16 + lo] = (__bf16)v;
    }
  }
  __syncthreads();
  bf16x8 h1a = *reinterpret_cast<const bf16x8*>(hrow + m * 72 + g * 8);
  bf16x8 h1b = *reinterpret_cast<const bf16x8*>(hrow + m * 72 + 32 + g * 8);

  // layer 2 + max over neighbors + store (f32)
  size_t obase = ((size_t)(x * BB + b) * CH) * NN;
#pragma unroll
  for (int tt = 0; tt < 4; ++tt) {
    float bv = cn[BM2_C + tt * 16 + lo];
    f32x4 acc = {bv, bv, bv, bv};
    acc = __builtin_amdgcn_mfma_f32_16x16x32_bf16(h1a, w2f[tt][0], acc, 0, 0, 0);
    acc = __builtin_amdgcn_mfma_f32_16x16x32_bf16(h1b, w2f[tt][1], acc, 0, 0, 0);
    float v = fmaxf(fmaxf(lrelu(acc[0]), lrelu(acc[1])), fmaxf(lrelu(acc[2]), lrelu(acc[3])));
    v = fmaxf(v, __shfl_xor(v, 16, 64));
    v = fmaxf(v, __shfl_xor(v, 32, 64));
    if (g == 0) out[obase + (size_t)(tt * 16 + lo) * NN + q] = v;
  }
}

// workspace layout (float units) — total ~5.64M floats = 22.6 MB
#define CN_OFF 0
#define FB_OFF ((size_t)CN_TOTAL)                      // 2,163,200
#define KT_OFF (FB_OFF + (size_t)4 * BB * NN * CH)     // +2,097,152
#define XZ_OFF (KT_OFF + (size_t)2 * BB * NN * CH)     // +1,048,576
#define WP4_OFF (XZ_OFF + (size_t)2 * BB * NN * 4)     // +65,536
#define WMB_OFF (WP4_OFF + 256)                        // 8192 bf16 = 4096 floats
#define IDX_OFF (WMB_OFF + 4096)                       // 262,144 ints
#define FLAG_OFF (IDX_OFF + 262144)                    // 1 int

extern "C" void kernel_launch(void* const* d_in, const int* in_sizes, int n_in,
                              void* d_out, int out_size, void* d_ws, size_t ws_size,
                              hipStream_t stream) {
  float* ws = (float*)d_ws;
  float* cn = ws + CN_OFF;
  int* flag = (int*)(ws + FLAG_OFF);

  k_detect<<<1, 64, 0, stream>>>((const unsigned short*)d_in[0], flag);
  k_ingest<<<(CN_TOTAL + 255) / 256, 256, 0, stream>>>(
      d_in[0], d_in[1], d_in[2], d_in[3], d_in[4], d_in[5], d_in[6], d_in[7],
      d_in[8], d_in[9], d_in[10], d_in[11], d_in[12], d_in[13], d_in[14], d_in[15],
      flag, cn);
  k_prep_wm<<<32, 256, 0, stream>>>(cn, (__hip_bfloat16*)(ws + WMB_OFF));
  k_prep_xyz<<<(2 * BB * NN) / 256, 256, 0, stream>>>(cn, (float4*)(ws + XZ_OFF));
  k_prep_wpos<<<1, 64, 0, stream>>>(cn, (float4*)(ws + WP4_OFF));
  k_prep_knn<<<(2 * BB * NN) / 256, 256, 0, stream>>>(cn, ws + KT_OFF);
  k_conv<<<4 * BB * (NN / 4), 256, 0, stream>>>(cn, ws + FB_OFF);
  k_knn<<<2 * BB * (NN / 64), 512, 0, stream>>>(ws + KT_OFF, (const float4*)(ws + XZ_OFF),
                                                (int*)(ws + IDX_OFF));
  k_mlp<<<2 * BB * (NN / 4), 256, 0, stream>>>(ws + FB_OFF, (const float4*)(ws + XZ_OFF),
                                               (const int*)(ws + IDX_OFF), (const float4*)(ws + WP4_OFF),
                                               (const __hip_bfloat16*)(ws + WMB_OFF), cn,
                                               (float*)d_out);
}

// Round 6
// 834.869 us; speedup vs baseline: 1.0981x; 1.0640x over previous
//
#include <hip/hip_runtime.h>
#include <hip/hip_bf16.h>

#define BB 2
#define NN 4096
#define CH 64
#define KW 8            // waves (slices) per KNN block
#define KSL (NN / KW)   // 512 points per slice
#define KQ 32           // queries per KNN block (half-query-per-lane scheme)

typedef __bf16 bf16x8 __attribute__((ext_vector_type(8)));
typedef float f32x4 __attribute__((ext_vector_type(4)));

__device__ __forceinline__ float lrelu(float v) { return fmaxf(v, 0.1f * v); }
__device__ __forceinline__ float tobf(const __hip_bfloat16& h) { return __bfloat162float(h); }

// canonical f32 input region offsets (element offsets within cn)
#define PC1_C 0
#define PC2_C 24576
#define F1_C 49152
#define F2_C 573440
#define K1_C 1097728
#define K2_C 1622016
#define WT11_C 2146304
#define BT11_C 2150400
#define WT22_C 2150464
#define BT22_C 2154560
#define WPOS_C 2154624
#define BPOS_C 2154816
#define WM1_C 2154880
#define BM1_C 2158976
#define WM2_C 2159040
#define BM2_C 2163136
#define CN_TOTAL 2163200

// bubble-insert into sorted ascending top-8; compile-time indices (stays in regs)
__device__ __forceinline__ void insert8(float bd[8], int bi[8], float nd, int ni) {
#pragma unroll
  for (int p = 0; p < 8; ++p) {
    bool c = nd < bd[p];
    float td = c ? nd : bd[p];
    int ti = c ? ni : bi[p];
    nd = c ? bd[p] : nd;
    ni = c ? bi[p] : ni;
    bd[p] = td;
    bi[p] = ti;
  }
}

// ---- dtype detector: interpret pc1's first 4096 u16 words as bf16; f32 data's
// low mantissa halves produce ~45% exponents >= 140; true bf16 N(0,1) gives ~0.
__global__ void k_detect(const unsigned short* __restrict__ pc1raw, int* __restrict__ flag) {
  int lane = threadIdx.x;  // 64
  int bad = 0;
#pragma unroll
  for (int i = 0; i < 64; ++i) {
    unsigned short u = pc1raw[lane * 64 + i];
    int e = (u >> 7) & 0xFF;
    bad += (e >= 140) ? 1 : 0;  // |v| >= 2^13 or Inf/NaN
  }
#pragma unroll
  for (int s = 32; s; s >>= 1) bad += __shfl_xor(bad, s, 64);
  if (lane == 0) *flag = (bad > 16) ? 1 : 0;  // 1 = inputs are float32
}

// ---- ingest: convert all 16 inputs to canonical f32 (exact either way) + sanitize
__global__ __launch_bounds__(256) void k_ingest(
    const void* p0, const void* p1, const void* p2, const void* p3,
    const void* p4, const void* p5, const void* p6, const void* p7,
    const void* p8, const void* p9, const void* p10, const void* p11,
    const void* p12, const void* p13, const void* p14, const void* p15,
    const int* __restrict__ flag, float* __restrict__ dst) {
  const int cum[17] = {0, 24576, 49152, 573440, 1097728, 1622016, 2146304, 2150400,
                       2150464, 2154560, 2154624, 2154816, 2154880, 2158976, 2159040,
                       2163136, 2163200};
  size_t t = (size_t)blockIdx.x * 256 + threadIdx.x;
  if (t >= (size_t)CN_TOTAL) return;
  int seg = 0;
#pragma unroll
  for (int i = 1; i < 16; ++i) seg += (t >= (size_t)cum[i]) ? 1 : 0;
  size_t local = t - (size_t)cum[seg];
  const void* ptrs[16] = {p0, p1, p2, p3, p4, p5, p6, p7, p8, p9, p10, p11, p12, p13, p14, p15};
  const void* p = ptrs[seg];
  float v;
  if (*flag) v = ((const float*)p)[local];
  else       v = tobf(((const __hip_bfloat16*)p)[local]);
  if (!(v == v) || fabsf(v) > 1e30f) v = 0.f;  // sanitize (no-op on clean data)
  dst[t] = v;
}

// ---- Wm1/Wm2 -> bf16 canonical (row-major, Wm1 at [0,4096), Wm2 at [4096,8192))
__global__ void k_prep_wm(const float* __restrict__ cn, __hip_bfloat16* __restrict__ wmb) {
  int t = blockIdx.x * 256 + threadIdx.x;  // 8192
  float v = (t < 4096) ? cn[WM1_C + t] : cn[WM2_C + (t - 4096)];
  wmb[t] = __float2bfloat16(v);
}

// ---- prep: pc [B,3,N] f32 -> float4(x,y,z,|p|^2) [2][B][N]
__global__ __launch_bounds__(256) void k_prep_xyz(const float* __restrict__ cn,
                                                  float4* __restrict__ xyzt) {
  int t = blockIdx.x * 256 + threadIdx.x;  // 2*BB*NN threads
  int n = t & (NN - 1);
  int b = (t >> 12) & 1;
  int a = t >> 13;
  const float* p = cn + (a ? PC2_C : PC1_C) + (size_t)b * 3 * NN + n;
  float x = p[0], y = p[NN], z = p[2 * NN];
  xyzt[(size_t)(a * BB + b) * NN + n] = make_float4(x, y, z, x * x + y * y + z * z);
}

// ---- prep: W_pos [64,3] + b_pos [64] -> float4 per channel
__global__ void k_prep_wpos(const float* __restrict__ cn, float4* __restrict__ wp4) {
  int c = threadIdx.x;  // 64
  wp4[c] = make_float4(cn[WPOS_C + 3 * c], cn[WPOS_C + 3 * c + 1], cn[WPOS_C + 3 * c + 2],
                       cn[BPOS_C + c]);
}

// ---- prep: knn [B,64,N] f32 -> row-normalized f32 [2][B][N][64]  (ref: x/sqrt(sum+1e-8))
__global__ __launch_bounds__(256) void k_prep_knn(const float* __restrict__ cn,
                                                  float* __restrict__ knnt) {
  int t = blockIdx.x * 256 + threadIdx.x;  // 2*BB*NN
  int n = t & (NN - 1);
  int b = (t >> 12) & 1;
  int a = t >> 13;
  const float* col = cn + (a ? K2_C : K1_C) + (size_t)b * CH * NN + n;
  float s = 0.f;
#pragma unroll
  for (int c = 0; c < CH; ++c) { float v = col[(size_t)c * NN]; s += v * v; }
  float inv = 1.0f / sqrtf(s + 1e-8f);
  float* o = knnt + ((size_t)(a * BB + b) * NN + n) * CH;
#pragma unroll
  for (int c = 0; c < CH; ++c) o[c] = col[(size_t)c * NN] * inv;
}

// ---- 1x1 convs: fbuf[sel][b][n][64], sel: 0=f1a(W11,f1) 1=f2a(W22,f2) 2=f2b(W11,f2) 3=f1b(W22,f1)
__global__ __launch_bounds__(256) void k_conv(const float* __restrict__ cn,
                                              float* __restrict__ fbuf) {
  __shared__ float wl[CH * CH];  // [c][d]
  int bid = blockIdx.x;          // 4*BB*(NN/4)
  int tile = bid & (NN / 4 - 1);
  int b = (bid >> 10) & 1;
  int sel = bid >> 11;
  const float* W = cn + ((sel == 0 || sel == 2) ? WT11_C : WT22_C);
  const float* bias = cn + ((sel == 0 || sel == 2) ? BT11_C : BT22_C);
  const float* feat = cn + ((sel == 0 || sel == 3) ? F1_C : F2_C);
  int t = threadIdx.x;
#pragma unroll
  for (int i = 0; i < 16; ++i) {
    int e = t * 16 + i;  // W[d][c] row-major -> wl[c][d]
    wl[(e & 63) * 64 + (e >> 6)] = W[e];
  }
  __syncthreads();
  int p = t >> 6, d = t & 63;
  int n = tile * 4 + p;
  const float* fc = feat + (size_t)b * CH * NN + n;
  float acc = bias[d];
#pragma unroll
  for (int c = 0; c < CH; ++c) acc += wl[c * 64 + d] * fc[(size_t)c * NN];
  fbuf[((size_t)(sel * BB + b) * NN + n) * CH + d] = acc;
}

// ---- fused KNN (cos + euclid), in-block slice merge.
// R5 post-mortem: lane-holds-full-query (64 f32) spills at the compiler's
// observed ~84-VGPR comfort zone -> per-j scratch reloads + addr VALU made the
// kernel issue-bound (VALUBusy 52%, 5x the pure-FMA instr count).
// New scheme: lane l holds HALF a query: channels [32*(l>>5), +32) of query
// (l&31) -> qv = 32 VGPRs, resident. Partial dots combined with one
// __shfl_xor(part, 32). Block = 8 slice-waves x 32 queries; 512 blocks (2/CU).
__global__ __launch_bounds__(512, 4) void k_knn(const float* __restrict__ knnt,
                                                const float4* __restrict__ xyzt,
                                                int* __restrict__ idxf) {
  __shared__ float cds[KW * KQ * 8];  // 8 KB
  __shared__ int   cis[KW * KQ * 8];  // 8 KB
  int bid = blockIdx.x;  // 2*BB*(NN/KQ) = 512:  x(1) | b(1) | qt(7)
  int qt = bid & (NN / KQ - 1);
  int b = (bid >> 7) & 1;
  int x = bid >> 8;
  int w = threadIdx.x >> 6;
  int lane = threadIdx.x & 63;
  int lq = lane & 31;       // local query
  int half = lane >> 5;     // channel half (0: ch 0..31, 1: ch 32..63)
  int q = qt * KQ + lq;
  int j0 = w * KSL;

  float bd[8]; int bi[8];

  // ---- phase 1: cosine scan over this wave's slice
  {
    const float4* qp = reinterpret_cast<const float4*>(
        knnt + ((size_t)(x * BB + b) * NN + q) * CH + half * 32);
    float4 qv[8];  // 32 VGPRs — resident
#pragma unroll
    for (int i = 0; i < 8; ++i) qv[i] = qp[i];
    const float* db = knnt + (size_t)((1 - x) * BB + b) * NN * CH + half * 32;
#pragma unroll
    for (int k = 0; k < 8; ++k) { bd[k] = 1e30f; bi[k] = 0; }
#pragma unroll 2
    for (int j = j0; j < j0 + KSL; ++j) {
      const float4* dp = reinterpret_cast<const float4*>(db + (size_t)j * CH);
      float ax = 0.f, ay = 0.f, az = 0.f, aw = 0.f;  // 4 chains for ILP
#pragma unroll
      for (int i = 0; i < 8; ++i) {
        float4 dv = dp[i];  // uniform within each half-wave
        ax += dv.x * qv[i].x; ay += dv.y * qv[i].y;
        az += dv.z * qv[i].z; aw += dv.w * qv[i].w;
      }
      float part = (ax + ay) + (az + aw);
      float dist = 1.0f - (part + __shfl_xor(part, 32, 64));  // combine halves
      if (dist < bd[7]) insert8(bd, bi, dist, j);
    }
    if (half == 0) {
#pragma unroll
      for (int k = 0; k < 8; ++k) {
        cds[(w * KQ + lq) * 8 + k] = bd[k];
        cis[(w * KQ + lq) * 8 + k] = bi[k];
      }
    }
  }
  __syncthreads();
  if (w == 0 && half == 0) {  // merge cosine candidates for this lane's query
#pragma unroll
    for (int k = 0; k < 8; ++k) { bd[k] = 1e30f; bi[k] = 0; }
    for (int c = 0; c < KW * 8; ++c) {
      int ww = c >> 3, k = c & 7;
      float d = cds[(ww * KQ + lq) * 8 + k];
      if (d < bd[7]) insert8(bd, bi, d, cis[(ww * KQ + lq) * 8 + k]);
    }
    int* o = idxf + (((size_t)x * BB + b) * NN + q) * 16;
#pragma unroll
    for (int k = 0; k < 8; ++k) o[k] = bi[k];
  }
  __syncthreads();

  // ---- phase 2: euclid scan (reuse LDS; halves compute duplicate work — cheap)
  {
    float4 q4 = xyzt[(size_t)(x * BB + b) * NN + q];
    const float4* dbx = xyzt + (size_t)((1 - x) * BB + b) * NN;
#pragma unroll
    for (int k = 0; k < 8; ++k) { bd[k] = 1e30f; bi[k] = 0; }
#pragma unroll 2
    for (int j = j0; j < j0 + KSL; ++j) {
      float4 p = dbx[j];  // wave-uniform
      float dist = q4.w + p.w - 2.f * (q4.x * p.x + q4.y * p.y + q4.z * p.z);
      if (dist < bd[7]) insert8(bd, bi, dist, j);
    }
    if (half == 0) {
#pragma unroll
      for (int k = 0; k < 8; ++k) {
        cds[(w * KQ + lq) * 8 + k] = bd[k];
        cis[(w * KQ + lq) * 8 + k] = bi[k];
      }
    }
  }
  __syncthreads();
  if (w == 0 && half == 0) {
#pragma unroll
    for (int k = 0; k < 8; ++k) { bd[k] = 1e30f; bi[k] = 0; }
    for (int c = 0; c < KW * 8; ++c) {
      int ww = c >> 3, k = c & 7;
      float d = cds[(ww * KQ + lq) * 8 + k];
      if (d < bd[7]) insert8(bd, bi, d, cis[(ww * KQ + lq) * 8 + k]);
    }
    int* o = idxf + (((size_t)x * BB + b) * NN + q) * 16 + 8;
#pragma unroll
    for (int k = 0; k < 8; ++k) o[k] = bi[k];
  }
}

// ---- fused gather + pos-conv + 2x MFMA MLP + neighbor max. One wave per query.
// M=16 neighbors, N=16-ch chunks (x4), K=32 (x2). A-frag: m=lane&15, k=(lane>>4)*8+j.
// B-frag: n=lane&15, k=(lane>>4)*8+j. D: col=lane&15, row=(lane>>4)*4+reg (m89/m120).
// Output: FLOAT32 (reference returns jnp.float32).
__global__ __launch_bounds__(256) void k_mlp(const float* __restrict__ fbuf,
                                             const float4* __restrict__ xyzt,
                                             const int* __restrict__ idxf,
                                             const float4* __restrict__ wp4,
                                             const __hip_bfloat16* __restrict__ wmb,
                                             const float* __restrict__ cn,
                                             float* __restrict__ out) {
  __shared__ __bf16 h1s[4 * 16 * 72];  // per-wave 16 rows x stride 72 (16B-aligned rows)
  const int t = threadIdx.x;
  const int wv = t >> 6, L = t & 63;
  const int lo = L & 15, g = L >> 4;
  int bid = blockIdx.x;  // 2*BB*(NN/4) = 4096
  const int qt = bid & (NN / 4 - 1);
  const int b = (bid >> 10) & 1;
  const int x = bid >> 11;
  const int q = qt * 4 + wv;

  // weight B-fragments resident in VGPRs: frag[tt][kc][j] = W[tt*16+lo][kc*32+g*8+j]
  bf16x8 w1f[4][2], w2f[4][2];
#pragma unroll
  for (int tt = 0; tt < 4; ++tt)
#pragma unroll
    for (int kc = 0; kc < 2; ++kc) {
      int e = tt * 16 + lo, c0 = kc * 32 + g * 8;
      w1f[tt][kc] = *reinterpret_cast<const bf16x8*>(wmb + e * 64 + c0);
      w2f[tt][kc] = *reinterpret_cast<const bf16x8*>(wmb + 4096 + e * 64 + c0);
    }

  const float* pq  = fbuf + ((size_t)((x ? 2 : 0) * BB + b)) * NN * CH;
  const float* pdb = fbuf + ((size_t)((x ? 3 : 1) * BB + b)) * NN * CH;
  const float4* qx  = xyzt + (size_t)(x * BB + b) * NN;
  const float4* dbx = xyzt + (size_t)((1 - x) * BB + b) * NN;

  const int m = lo;  // this lane's neighbor slot
  int jm = idxf[(((size_t)x * BB + b) * NN + q) * 16 + m];
  jm &= (NN - 1);  // defensive clamp: garbage idx -> finite-wrong, never OOB
  const float4 q4 = qx[q];
  const float4 p4 = dbx[jm];
  const float dx = p4.x - q4.x, dy = p4.y - q4.y, dz = p4.z - q4.z;
  const float* g2p = pdb + (size_t)jm * CH;
  const float* pqp = pq + (size_t)q * CH;

  // H0 built directly in A-fragment layout
  bf16x8 a0, a1;
#pragma unroll
  for (int kc = 0; kc < 2; ++kc) {
#pragma unroll
    for (int j = 0; j < 8; ++j) {
      int c = kc * 32 + g * 8 + j;
      float4 wp = wp4[c];
      float v = g2p[c] + pqp[c] + wp.x * dx + wp.y * dy + wp.z * dz + wp.w;
      v = lrelu(v);
      if (kc == 0) a0[j] = (__bf16)v; else a1[j] = (__bf16)v;
    }
  }

  // layer 1 -> LDS (D-layout write, A-layout read)
  __bf16* hrow = h1s + wv * 16 * 72;
#pragma unroll
  for (int tt = 0; tt < 4; ++tt) {
    float bv = cn[BM1_C + tt * 16 + lo];
    f32x4 acc = {bv, bv, bv, bv};
    acc = __builtin_amdgcn_mfma_f32_16x16x32_bf16(a0, w1f[tt][0], acc, 0, 0, 0);
    acc = __builtin_amdgcn_mfma_f32_16x16x32_bf16(a1, w1f[tt][1], acc, 0, 0, 0);
#pragma unroll
    for (int r = 0; r < 4; ++r) {
      float v = lrelu(acc[r]);
      hrow[(g * 4 + r) * 72 + tt * 16 + lo] = (__bf16)v;
    }
  }
  __syncthreads();
  bf16x8 h1a = *reinterpret_cast<const bf16x8*>(hrow + m * 72 + g * 8);
  bf16x8 h1b = *reinterpret_cast<const bf16x8*>(hrow + m * 72 + 32 + g * 8);

  // layer 2 + max over neighbors + store (f32)
  size_t obase = ((size_t)(x * BB + b) * CH) * NN;
#pragma unroll
  for (int tt = 0; tt < 4; ++tt) {
    float bv = cn[BM2_C + tt * 16 + lo];
    f32x4 acc = {bv, bv, bv, bv};
    acc = __builtin_amdgcn_mfma_f32_16x16x32_bf16(h1a, w2f[tt][0], acc, 0, 0, 0);
    acc = __builtin_amdgcn_mfma_f32_16x16x32_bf16(h1b, w2f[tt][1], acc, 0, 0, 0);
    float v = fmaxf(fmaxf(lrelu(acc[0]), lrelu(acc[1])), fmaxf(lrelu(acc[2]), lrelu(acc[3])));
    v = fmaxf(v, __shfl_xor(v, 16, 64));
    v = fmaxf(v, __shfl_xor(v, 32, 64));
    if (g == 0) out[obase + (size_t)(tt * 16 + lo) * NN + q] = v;
  }
}

// workspace layout (float units) — total ~5.64M floats = 22.6 MB
#define CN_OFF 0
#define FB_OFF ((size_t)CN_TOTAL)                      // 2,163,200
#define KT_OFF (FB_OFF + (size_t)4 * BB * NN * CH)     // +2,097,152
#define XZ_OFF (KT_OFF + (size_t)2 * BB * NN * CH)     // +1,048,576
#define WP4_OFF (XZ_OFF + (size_t)2 * BB * NN * 4)     // +65,536
#define WMB_OFF (WP4_OFF + 256)                        // 8192 bf16 = 4096 floats
#define IDX_OFF (WMB_OFF + 4096)                       // 262,144 ints
#define FLAG_OFF (IDX_OFF + 262144)                    // 1 int

extern "C" void kernel_launch(void* const* d_in, const int* in_sizes, int n_in,
                              void* d_out, int out_size, void* d_ws, size_t ws_size,
                              hipStream_t stream) {
  float* ws = (float*)d_ws;
  float* cn = ws + CN_OFF;
  int* flag = (int*)(ws + FLAG_OFF);

  k_detect<<<1, 64, 0, stream>>>((const unsigned short*)d_in[0], flag);
  k_ingest<<<(CN_TOTAL + 255) / 256, 256, 0, stream>>>(
      d_in[0], d_in[1], d_in[2], d_in[3], d_in[4], d_in[5], d_in[6], d_in[7],
      d_in[8], d_in[9], d_in[10], d_in[11], d_in[12], d_in[13], d_in[14], d_in[15],
      flag, cn);
  k_prep_wm<<<32, 256, 0, stream>>>(cn, (__hip_bfloat16*)(ws + WMB_OFF));
  k_prep_xyz<<<(2 * BB * NN) / 256, 256, 0, stream>>>(cn, (float4*)(ws + XZ_OFF));
  k_prep_wpos<<<1, 64, 0, stream>>>(cn, (float4*)(ws + WP4_OFF));
  k_prep_knn<<<(2 * BB * NN) / 256, 256, 0, stream>>>(cn, ws + KT_OFF);
  k_conv<<<4 * BB * (NN / 4), 256, 0, stream>>>(cn, ws + FB_OFF);
  k_knn<<<2 * BB * (NN / KQ), 512, 0, stream>>>(ws + KT_OFF, (const float4*)(ws + XZ_OFF),
                                                (int*)(ws + IDX_OFF));
  k_mlp<<<2 * BB * (NN / 4), 256, 0, stream>>>(ws + FB_OFF, (const float4*)(ws + XZ_OFF),
                                               (const int*)(ws + IDX_OFF), (const float4*)(ws + WP4_OFF),
                                               (const __hip_bfloat16*)(ws + WMB_OFF), cn,
                                               (float*)d_out);
}